// Round 5
// baseline (279.368 us; speedup 1.0000x reference)
//
#include <hip/hip_runtime.h>
#include <hip/hip_bf16.h>
#include <math.h>

#define H 1024
#define R 64
#define BM 64        // rows per block, 4 waves: K-split down-proj, col-split up-proj
#define NTHREADS 256
#define TSTRIDE 72   // t_lds row stride (shorts)
#define PSTRIDE 20   // partial buf col-major stride (floats), 16B-aligned, bank-spread

typedef __attribute__((ext_vector_type(8))) short short8;
typedef __attribute__((ext_vector_type(4))) float floatx4;

__device__ __forceinline__ unsigned short f2bf(float f) {
    unsigned int u = __builtin_bit_cast(unsigned int, f);
    u += 0x7fffu + ((u >> 16) & 1u);   // round-to-nearest-even
    return (unsigned short)(u >> 16);
}

// ---- prep: weights -> bf16 MFMA B-fragments (gamma folded into W_down) ----
// frag f, lane l, elem j -> ws[(f*64+l)*8+j]; k = (l>>4)*8 + j within k-tile
__global__ void prep_weights(const float* __restrict__ w_down,
                             const float* __restrict__ w_up,
                             const float* __restrict__ gamma,
                             unsigned short* __restrict__ wsd,
                             unsigned short* __restrict__ wsu) {
    int tid = blockIdx.x * blockDim.x + threadIdx.x;   // 0..65535
    int j    = tid & 7;
    int lane = (tid >> 3) & 63;
    int f    = tid >> 9;                               // 0..127
    int b = lane >> 4, p = lane & 15;
    {   // W' = gamma * W_down: f = kk*4 + n
        int kk = f >> 2, n = f & 3;
        int row = kk * 32 + b * 8 + j;
        int col = n * 16 + p;
        wsd[tid] = f2bf(gamma[row] * w_down[row * R + col]);
    }
    {   // W_up: f = ks*64 + n
        int ks = f >> 6, n = f & 63;
        int row = ks * 32 + b * 8 + j;
        int col = n * 16 + p;
        wsu[tid] = f2bf(w_up[row * H + col]);
    }
}

// ---- prep: w1[r] = sum_h gamma[h]*W_down[h][r]; c0[r] = sum_h beta[h]*W_down[h][r] + b_down[r]
__global__ void prep_vec(const float* __restrict__ w_down,
                         const float* __restrict__ gamma,
                         const float* __restrict__ beta,
                         const float* __restrict__ b_down,
                         float* __restrict__ w1, float* __restrict__ c0) {
    int r = blockIdx.x;          // 0..63
    int t = threadIdx.x;         // 256 threads
    float a = 0.f, c = 0.f;
    for (int h = t; h < H; h += NTHREADS) {
        float wd = w_down[h * R + r];
        a += gamma[h] * wd;
        c += beta[h] * wd;
    }
    #pragma unroll
    for (int off = 32; off >= 1; off >>= 1) {
        a += __shfl_xor(a, off);
        c += __shfl_xor(c, off);
    }
    __shared__ float red[8];
    int wv = t >> 6;
    if ((t & 63) == 0) { red[wv] = a; red[4 + wv] = c; }
    __syncthreads();
    if (t == 0) {
        w1[r] = red[0] + red[1] + red[2] + red[3];
        c0[r] = red[4] + red[5] + red[6] + red[7] + b_down[r];
    }
}

__global__ __launch_bounds__(NTHREADS, 2)
void adapter_kernel(const float* __restrict__ x,
                    const float* __restrict__ b_up,
                    const unsigned short* __restrict__ wsd,
                    const unsigned short* __restrict__ wsu,
                    const float* __restrict__ w1v,
                    const float* __restrict__ c0v,
                    float* __restrict__ out) {
    __shared__ __align__(16) float part[12 * 64 * PSTRIDE];        // 60 KB: cross-wave partials
    __shared__ __align__(16) unsigned short t_lds[BM * TSTRIDE];   // 9 KB
    __shared__ float s1w[4][BM], s2w[4][BM];                       // 2 KB

    const int tid  = threadIdx.x;
    const int lane = tid & 63;
    const int w    = tid >> 6;       // wave: K-chunk owner (down), col-chunk owner (up)
    const int p    = lane & 15;
    const int b    = lane >> 4;
    const long rowbase = (long)blockIdx.x * BM;
    const int kbase = w * 256;

    // ---- phase 1: x loads (frag layout) + row stats + K-chunk down-GEMM ----
    float s1[4] = {0.f,0.f,0.f,0.f}, s2[4] = {0.f,0.f,0.f,0.f};
    floatx4 acc[4][4];               // [mt][nt]
    #pragma unroll
    for (int mt = 0; mt < 4; ++mt)
        #pragma unroll
        for (int nt = 0; nt < 4; ++nt)
            acc[mt][nt] = floatx4{0.f,0.f,0.f,0.f};

    const short8* wsd8 = (const short8*)wsd;
    #pragma unroll
    for (int kt = 0; kt < 8; ++kt) {
        short8 af[4];
        #pragma unroll
        for (int mt = 0; mt < 4; ++mt) {
            const float* px = x + (rowbase + mt * 16 + p) * H + kbase + kt * 32 + b * 8;
            floatx4 v0 = *(const floatx4*)px;
            floatx4 v1 = *(const floatx4*)(px + 4);
            short8 a;
            #pragma unroll
            for (int e = 0; e < 4; ++e) {
                s1[mt] += v0[e] + v1[e];
                s2[mt] += v0[e] * v0[e] + v1[e] * v1[e];
                a[e]     = (short)f2bf(v0[e]);
                a[4 + e] = (short)f2bf(v1[e]);
            }
            af[mt] = a;
        }
        #pragma unroll
        for (int nt = 0; nt < 4; ++nt) {
            short8 bfrag = wsd8[(size_t)((w * 8 + kt) * 4 + nt) * 64 + lane];
            #pragma unroll
            for (int mt = 0; mt < 4; ++mt)
                acc[mt][nt] = __builtin_amdgcn_mfma_f32_16x16x32_bf16(af[mt], bfrag, acc[mt][nt], 0, 0, 0);
        }
    }

    // ---- stats: reduce over b (this wave's 256 k-elems per row), publish ----
    #pragma unroll
    for (int mt = 0; mt < 4; ++mt) {
        s1[mt] += __shfl_xor(s1[mt], 16); s1[mt] += __shfl_xor(s1[mt], 32);
        s2[mt] += __shfl_xor(s2[mt], 16); s2[mt] += __shfl_xor(s2[mt], 32);
    }
    if (b == 0) {
        #pragma unroll
        for (int mt = 0; mt < 4; ++mt) {
            s1w[w][mt * 16 + p] = s1[mt];
            s2w[w][mt * 16 + p] = s2[mt];
        }
    }

    // ---- partials: write non-owned m-tiles col-major [col][PSTRIDE] ----
    floatx4 own[4];
    #pragma unroll
    for (int mt = 0; mt < 4; ++mt) {
        if (mt != w) {
            int idx = w * 3 + (mt < w ? mt : mt - 1);
            float* dst = &part[idx * 64 * PSTRIDE];
            #pragma unroll
            for (int nt = 0; nt < 4; ++nt)
                *(floatx4*)&dst[(nt * 16 + p) * PSTRIDE + b * 4] = acc[mt][nt];
        } else {
            #pragma unroll
            for (int nt = 0; nt < 4; ++nt) own[nt] = acc[mt][nt];
        }
    }
    __syncthreads();

    // ---- phase 2: owner reduces its m-tile, applies folded LN + GELU -> t_lds
    #pragma unroll
    for (int src = 0; src < 3; ++src) {
        int ow  = (src < w) ? src : src + 1;          // contributing wave
        int idx = ow * 3 + (w < ow ? w : w - 1);      // its buffer for tile mt=w
        const float* sp = &part[idx * 64 * PSTRIDE];
        #pragma unroll
        for (int nt = 0; nt < 4; ++nt)
            own[nt] += *(const floatx4*)&sp[(nt * 16 + p) * PSTRIDE + b * 4];
    }
    float mu[4], rs[4];
    #pragma unroll
    for (int reg = 0; reg < 4; ++reg) {
        int row = w * 16 + b * 4 + reg;
        float a = s1w[0][row] + s1w[1][row] + s1w[2][row] + s1w[3][row];
        float q = s2w[0][row] + s2w[1][row] + s2w[2][row] + s2w[3][row];
        float m = a * (1.0f / (float)H);
        float var = q * (1.0f / (float)H) - m * m;
        mu[reg] = m;
        rs[reg] = rsqrtf(var + 1e-5f);
    }
    #pragma unroll
    for (int nt = 0; nt < 4; ++nt) {
        float wv1 = w1v[nt * 16 + p];
        float cv0 = c0v[nt * 16 + p];
        #pragma unroll
        for (int reg = 0; reg < 4; ++reg) {
            float u = rs[reg] * (own[nt][reg] - mu[reg] * wv1) + cv0;
            u = 0.5f * u * (1.0f + erff(u * 0.70710678f));
            t_lds[(w * 16 + b * 4 + reg) * TSTRIDE + nt * 16 + p] = f2bf(u);
        }
    }
    __syncthreads();

    // ---- phase 3: up-proj (wave owns cols [w*256,(w+1)*256)) + b_up + residual
    short8 a0[4], a1[4];
    #pragma unroll
    for (int mt = 0; mt < 4; ++mt) {
        a0[mt] = *(const short8*)&t_lds[(mt * 16 + p) * TSTRIDE + b * 8];
        a1[mt] = *(const short8*)&t_lds[(mt * 16 + p) * TSTRIDE + 32 + b * 8];
    }
    const short8* wsu8 = (const short8*)wsu;
    #pragma unroll 2
    for (int nn = 0; nn < 16; ++nn) {
        int n = w * 16 + nn;
        short8 bu0 = wsu8[(size_t)n * 64 + lane];
        short8 bu1 = wsu8[(size_t)(64 + n) * 64 + lane];
        int col = n * 16 + p;
        float bup = b_up[col];
        #pragma unroll
        for (int mt = 0; mt < 4; ++mt) {
            floatx4 av = {0.f, 0.f, 0.f, 0.f};
            av = __builtin_amdgcn_mfma_f32_16x16x32_bf16(a0[mt], bu0, av, 0, 0, 0);
            av = __builtin_amdgcn_mfma_f32_16x16x32_bf16(a1[mt], bu1, av, 0, 0, 0);
            #pragma unroll
            for (int reg = 0; reg < 4; ++reg) {
                long rr = rowbase + mt * 16 + b * 4 + reg;
                out[rr * H + col] = av[reg] + bup + x[rr * H + col];
            }
        }
    }
}

extern "C" void kernel_launch(void* const* d_in, const int* in_sizes, int n_in,
                              void* d_out, int out_size, void* d_ws, size_t ws_size,
                              hipStream_t stream) {
    const float* x      = (const float*)d_in[0];
    const float* gamma  = (const float*)d_in[1];
    const float* beta   = (const float*)d_in[2];
    const float* w_down = (const float*)d_in[3];
    const float* b_down = (const float*)d_in[4];
    const float* w_up   = (const float*)d_in[5];
    const float* b_up   = (const float*)d_in[6];
    float* out = (float*)d_out;

    unsigned short* wsd = (unsigned short*)d_ws;
    unsigned short* wsu = wsd + 65536;
    float* w1 = (float*)(wsu + 65536);
    float* c0 = w1 + 64;

    int M = in_sizes[0] / H;                 // 32768 rows
    prep_weights<<<256, 256, 0, stream>>>(w_down, w_up, gamma, wsd, wsu);
    prep_vec<<<64, 256, 0, stream>>>(w_down, gamma, beta, b_down, w1, c0);
    adapter_kernel<<<M / BM, NTHREADS, 0, stream>>>(x, b_up, wsd, wsu, w1, c0, out);
}